// Round 3
// baseline (290.284 us; speedup 1.0000x reference)
//
#include <hip/hip_runtime.h>

#define NL 64
#define SQ 512
#define BATCH 1024

typedef __fp16   hf2   __attribute__((ext_vector_type(2)));
typedef _Float16 h8    __attribute__((ext_vector_type(8)));
typedef float    f32x4 __attribute__((ext_vector_type(4)));
typedef int      i32x4 __attribute__((ext_vector_type(4)));

#define EXP2F(x)  __builtin_amdgcn_exp2f(x)   // 2^x (v_exp_f32)
#define LOG2F(x)  __builtin_amdgcn_logf(x)    // log2 (v_log_f32)
#define MFMA16(a,b,c) __builtin_amdgcn_mfma_f32_16x16x32_f16((a),(b),(c),0,0,0)

static __device__ __forceinline__ int pkf16(float a, float b) {
    return __builtin_bit_cast(int, __builtin_amdgcn_cvt_pkrtz(a, b));
}

// Round-9: MFMA-batched CRF scan. 16 chains per wave, step is a 64x64 x 64x16
// GEMM on the matrix pipe: D[j_out][chain] = sum_i A[j_out][i] * B[i][chain],
// A = exp(T)^T (fwd) / exp(T) (bwd), held as 8 resident A-frags (32 VGPR).
// KEY LAYOUT FACT: with chains on N, the C/D frag (col=lane&15=chain,
// row=4*(lane>>4)+reg) and the B frag (col=lane&15=chain,
// k=16*(e>>2)+4*(lane>>4)+(e&3)) occupy the SAME lanes: lane (c,g)'s 16
// state values ARE its next-step B elements -> D->B is a pure within-lane
// repack (8 cvt_pkrtz). No LDS, no cross-lane, except one ds_bpermute per
// step to broadcast the chain's state-0 value for the exponent-bit renorm
// (exact power-of-2 scale, as in round 7/8).
// A/B k-mapping: two-half form k=16*(e>>2)+4g+(e&3) (matches the HW-verified
// ds_read_b64_tr_b16 pattern, m162). FALLBACK if validation fails: k=8g+e.
// Numerics identical in structure to round-7 (f16 window [~5e-5,~1.4e3],
// anchor in [0.125,0.25), f32 accumulate).
__global__ __launch_bounds__(64, 1) void crf_scan_mfma(
    const float* __restrict__ emissions,   // [B, S, L]
    const int*   __restrict__ mask,        // [B, S]
    const float* __restrict__ trans,       // [L, L]
    const float* __restrict__ start_t,     // [L]
    const float* __restrict__ end_t,       // [L]
    float* __restrict__ ws_p,              // [2B][64]
    float* __restrict__ ws_c)              // [2B]  (log2-domain offsets)
{
    const int  blk  = blockIdx.x;          // 0..127
    const bool fwd  = blk < 64;
    const int  cbase = (fwd ? blk : blk - 64) * 16;
    const int  l  = threadIdx.x;
    const int  cl = l & 15;                // chain-in-group == MFMA col
    const int  g  = l >> 4;                // 4-lane group == row/k quarter
    const int  chain = cbase + cl;
    const float LOG2E = 1.44269504088896340736f;

    const float* em = emissions + (size_t)chain * SQ * NL;   // this lane's chain
    const int*   mk = mask + (size_t)chain * SQ;
    const int    bpa = cl * 4;             // bpermute byte addr: lane cl (g==0)

    // Resident A fragments: A[m][ks], rows j = 16m + cl, k = i state.
    h8 Afr[4][2];
#pragma unroll
    for (int m = 0; m < 4; ++m) {
#pragma unroll
        for (int ks = 0; ks < 2; ++ks) {
            i32x4 w;
#pragma unroll
            for (int ep = 0; ep < 4; ++ep) {
                const int e0 = 2*ep, e1 = 2*ep + 1;
                const int k0 = 32*ks + 16*(e0>>2) + 4*g + (e0&3);
                const int k1 = 32*ks + 16*(e1>>2) + 4*g + (e1&3);
                float v0, v1;
                if (fwd) { v0 = __expf(trans[k0*NL + (16*m + cl)]);   // ET^T[j][i]
                           v1 = __expf(trans[k1*NL + (16*m + cl)]); }
                else     { v0 = __expf(trans[(16*m + cl)*NL + k0]);   // ET[i][j]
                           v1 = __expf(trans[(16*m + cl)*NL + k1]); }
                w[ep] = pkf16(v0, v1);
            }
            Afr[m][ks] = __builtin_bit_cast(h8, w);
        }
    }

    const f32x4 zz = {0.f, 0.f, 0.f, 0.f};
    f32x4 pD[4];          // state, D-layout: pD[m][r] = P[chain cl][16m+4g+r]
    float basec = 0.f;
    int   esum  = 0;

    // ---- fwd step: p_new = exp(em_t) .* (A x (p*scale)), masked ----
    auto stepF = [&](const f32x4 (&E)[4], int mm) {
        f32x4 ex[4];
#pragma unroll
        for (int m = 0; m < 4; ++m)
#pragma unroll
            for (int r = 0; r < 4; ++r) ex[m][r] = EXP2F(E[m][r] * LOG2E);
        const int anci = __builtin_amdgcn_ds_bpermute(bpa, __float_as_int(pD[0][0]));
        const unsigned u = (unsigned)anci;
        const int eb = (int)((u >> 23) & 0xffu);
        const float sc = __uint_as_float((unsigned)(251 - eb) << 23);  // 2^(124-eb)
        i32x4 w0, w1;
        w0[0] = pkf16(pD[0][0]*sc, pD[0][1]*sc); w0[1] = pkf16(pD[0][2]*sc, pD[0][3]*sc);
        w0[2] = pkf16(pD[1][0]*sc, pD[1][1]*sc); w0[3] = pkf16(pD[1][2]*sc, pD[1][3]*sc);
        w1[0] = pkf16(pD[2][0]*sc, pD[2][1]*sc); w1[1] = pkf16(pD[2][2]*sc, pD[2][3]*sc);
        w1[2] = pkf16(pD[3][0]*sc, pD[3][1]*sc); w1[3] = pkf16(pD[3][2]*sc, pD[3][3]*sc);
        const h8 B0 = __builtin_bit_cast(h8, w0);
        const h8 B1 = __builtin_bit_cast(h8, w1);
        f32x4 ac[4];
#pragma unroll
        for (int m = 0; m < 4; ++m) {
            ac[m] = MFMA16(Afr[m][0], B0, zz);
            ac[m] = MFMA16(Afr[m][1], B1, ac[m]);
        }
#pragma unroll
        for (int m = 0; m < 4; ++m)
#pragma unroll
            for (int r = 0; r < 4; ++r)
                pD[m][r] = mm ? (ex[m][r] * ac[m][r]) : pD[m][r];
        esum += mm ? (eb - 124) : 0;
    };

    // ---- bwd step: p_new = A x ((exp(em_t).*p)*scale), masked ----
    auto stepB = [&](const f32x4 (&E)[4], int mm) {
        f32x4 scv[4];
#pragma unroll
        for (int m = 0; m < 4; ++m)
#pragma unroll
            for (int r = 0; r < 4; ++r)
                scv[m][r] = EXP2F(E[m][r] * LOG2E) * pD[m][r];
        const int anci = __builtin_amdgcn_ds_bpermute(bpa, __float_as_int(scv[0][0]));
        const unsigned u = (unsigned)anci;
        const int eb = (int)((u >> 23) & 0xffu);
        const float sc = __uint_as_float((unsigned)(251 - eb) << 23);
        i32x4 w0, w1;
        w0[0] = pkf16(scv[0][0]*sc, scv[0][1]*sc); w0[1] = pkf16(scv[0][2]*sc, scv[0][3]*sc);
        w0[2] = pkf16(scv[1][0]*sc, scv[1][1]*sc); w0[3] = pkf16(scv[1][2]*sc, scv[1][3]*sc);
        w1[0] = pkf16(scv[2][0]*sc, scv[2][1]*sc); w1[1] = pkf16(scv[2][2]*sc, scv[2][3]*sc);
        w1[2] = pkf16(scv[3][0]*sc, scv[3][1]*sc); w1[3] = pkf16(scv[3][2]*sc, scv[3][3]*sc);
        const h8 B0 = __builtin_bit_cast(h8, w0);
        const h8 B1 = __builtin_bit_cast(h8, w1);
        f32x4 ac[4];
#pragma unroll
        for (int m = 0; m < 4; ++m) {
            ac[m] = MFMA16(Afr[m][0], B0, zz);
            ac[m] = MFMA16(Afr[m][1], B1, ac[m]);
        }
#pragma unroll
        for (int m = 0; m < 4; ++m)
#pragma unroll
            for (int r = 0; r < 4; ++r)
                pD[m][r] = mm ? ac[m][r] : pD[m][r];
        esum += mm ? (eb - 124) : 0;
    };

    if (fwd) {
        // t = 0 init: alpha0 = start + em[0], anchor-normalized
        f32x4 s0[4];
#pragma unroll
        for (int m = 0; m < 4; ++m) {
            const f32x4 st = *reinterpret_cast<const f32x4*>(start_t + 16*m + 4*g);
            const f32x4 e0 = *reinterpret_cast<const f32x4*>(em + 16*m + 4*g);
            s0[m] = st + e0;
        }
        const int anci = __builtin_amdgcn_ds_bpermute(bpa, __float_as_int(s0[0][0]));
        const float anc = __int_as_float(anci);
        basec = anc * LOG2E;
#pragma unroll
        for (int m = 0; m < 4; ++m)
#pragma unroll
            for (int r = 0; r < 4; ++r)
                pD[m][r] = EXP2F((s0[m][r] - anc) * LOG2E);

        // peel t=1..3
        f32x4 P[3][4];
#pragma unroll
        for (int k = 0; k < 3; ++k)
#pragma unroll
            for (int m = 0; m < 4; ++m)
                P[k][m] = *reinterpret_cast<const f32x4*>(em + (size_t)(1+k)*NL + 16*m + 4*g);
        const i32x4 M0 = *reinterpret_cast<const i32x4*>(mk);

        // current group buffer t=4..7
        f32x4 C[4][4];
#pragma unroll
        for (int k = 0; k < 4; ++k)
#pragma unroll
            for (int m = 0; m < 4; ++m)
                C[k][m] = *reinterpret_cast<const f32x4*>(em + (size_t)(4+k)*NL + 16*m + 4*g);
        i32x4 Mc = *reinterpret_cast<const i32x4*>(mk + 4);

        stepF(P[0], M0[1]); stepF(P[1], M0[2]); stepF(P[2], M0[3]);

        for (int G = 0; G < 63; ++G) {         // groups t = 4..255
            const int t = 4 + 4*G;
            f32x4 Nb[4][4];
#pragma unroll
            for (int k = 0; k < 4; ++k)
#pragma unroll
                for (int m = 0; m < 4; ++m)
                    Nb[k][m] = *reinterpret_cast<const f32x4*>(em + (size_t)(t+4+k)*NL + 16*m + 4*g);
            const i32x4 Mn = *reinterpret_cast<const i32x4*>(mk + t + 4);

            stepF(C[0], Mc[0]); stepF(C[1], Mc[1]);
            stepF(C[2], Mc[2]); stepF(C[3], Mc[3]);

#pragma unroll
            for (int k = 0; k < 4; ++k)
#pragma unroll
                for (int m = 0; m < 4; ++m) C[k][m] = Nb[k][m];
            Mc = Mn;
        }
    } else {
        // init q_511 = exp(end)
#pragma unroll
        for (int m = 0; m < 4; ++m) {
            const f32x4 ev = *reinterpret_cast<const f32x4*>(end_t + 16*m + 4*g);
#pragma unroll
            for (int r = 0; r < 4; ++r) pD[m][r] = __expf(ev[r]);
        }
        basec = 0.f;

        f32x4 C[4][4];
#pragma unroll
        for (int k = 0; k < 4; ++k)
#pragma unroll
            for (int m = 0; m < 4; ++m)
                C[k][m] = *reinterpret_cast<const f32x4*>(em + (size_t)(511-k)*NL + 16*m + 4*g);
        i32x4 Mc = *reinterpret_cast<const i32x4*>(mk + 508);   // {508..511}

        for (int G = 0; G < 64; ++G) {         // groups t = 511 down to 256
            const int t0 = 511 - 4*G;
            const int tp = t0 - 4;             // next group's top (G=63 -> 255, unused)
            f32x4 Nb[4][4];
#pragma unroll
            for (int k = 0; k < 4; ++k)
#pragma unroll
                for (int m = 0; m < 4; ++m)
                    Nb[k][m] = *reinterpret_cast<const f32x4*>(em + (size_t)(tp-k)*NL + 16*m + 4*g);
            const i32x4 Mn = *reinterpret_cast<const i32x4*>(mk + (tp - 3));

            stepB(C[0], Mc[3]); stepB(C[1], Mc[2]);
            stepB(C[2], Mc[1]); stepB(C[3], Mc[0]);

#pragma unroll
            for (int k = 0; k < 4; ++k)
#pragma unroll
                for (int m = 0; m < 4; ++m) C[k][m] = Nb[k][m];
            Mc = Mn;
        }
    }

    // write out: slot = chain (+BATCH for bwd); lane (cl,g) owns states 16m+4g+0..3
    const int slot = (fwd ? 0 : BATCH) + chain;
#pragma unroll
    for (int m = 0; m < 4; ++m)
        *reinterpret_cast<f32x4*>(ws_p + (size_t)slot*NL + 16*m + 4*g) = pD[m];
    if (g == 0) ws_c[slot] = basec + (float)esum;
}

// out[b] = ln2 * ( c2f + c2b + log2( sum_j pf[j] * pb[j] ) )
__global__ __launch_bounds__(64) void crf_combine(
    const float* __restrict__ ws_p, const float* __restrict__ ws_c,
    float* __restrict__ out)
{
    const int b = blockIdx.x;
    const int j = threadIdx.x;
    float v = ws_p[(size_t)b * NL + j] * ws_p[(size_t)(b + BATCH) * NL + j];
#pragma unroll
    for (int off = 32; off; off >>= 1) v += __shfl_xor(v, off);
    if (j == 0)
        out[b] = 0.69314718055994530942f *
                 (ws_c[b] + ws_c[b + BATCH] + LOG2F(v));
}

extern "C" void kernel_launch(void* const* d_in, const int* in_sizes, int n_in,
                              void* d_out, int out_size, void* d_ws, size_t ws_size,
                              hipStream_t stream) {
    const float* emissions = (const float*)d_in[0];
    const int*   mask      = (const int*)d_in[1];
    const float* trans     = (const float*)d_in[2];
    const float* start_t   = (const float*)d_in[3];
    const float* end_t     = (const float*)d_in[4];
    float* out = (float*)d_out;

    float* ws_p = (float*)d_ws;                    // 2*1024*64 floats
    float* ws_c = ws_p + 2 * BATCH * NL;           // 2*1024 floats

    crf_scan_mfma<<<128, NL, 0, stream>>>(emissions, mask, trans,
                                          start_t, end_t, ws_p, ws_c);
    crf_combine<<<BATCH, NL, 0, stream>>>(ws_p, ws_c, out);
}